// Round 2
// baseline (37318.372 us; speedup 1.0000x reference)
//
#include <hip/hip_runtime.h>

typedef unsigned int u32;
typedef unsigned short u16;
typedef __attribute__((ext_vector_type(8))) short v8s;   // 8 bf16
typedef __attribute__((ext_vector_type(4))) float v4f;
typedef __attribute__((ext_vector_type(2))) float v2f;
typedef __attribute__((ext_vector_type(4))) u32 v4u;

__device__ __forceinline__ float bf2f(u16 v) { return __uint_as_float(((u32)v) << 16); }
__device__ __forceinline__ u16 f2bf(float f) {
    u32 u = __float_as_uint(f);
    return (u16)((u + 0x7fffu + ((u >> 16) & 1u)) >> 16);   // RNE
}
__device__ __forceinline__ float blo(u32 u) { return __uint_as_float(u << 16); }
__device__ __forceinline__ float bhi(u32 u) { return __uint_as_float(u & 0xffff0000u); }
__device__ __forceinline__ float sigf(float x) { return 1.0f / (1.0f + __expf(-x)); }
__device__ __forceinline__ v8s pack8(v4f a, v4f b) {
    v8s r;
    r[0] = (short)f2bf(a[0]); r[1] = (short)f2bf(a[1]);
    r[2] = (short)f2bf(a[2]); r[3] = (short)f2bf(a[3]);
    r[4] = (short)f2bf(b[0]); r[5] = (short)f2bf(b[1]);
    r[6] = (short)f2bf(b[2]); r[7] = (short)f2bf(b[3]);
    return r;
}

// ---------------------------------------------------------------------------
// GEMM: out[t][j] = sum_k A[t][k]*W[j][k] + bih[j] + bhh[j].
// A,W,b fp32 in; out bf16 (precomp). M=1024, N=4096, K in {768,1024}.
// 128x128 tile, 4 waves (2x2), 16x16x32 bf16 MFMA, fp32 accum.
// ---------------------------------------------------------------------------
__global__ __launch_bounds__(256) void gemm_ih(
    const float* __restrict__ A,    // [1024][K]
    const float* __restrict__ W,    // [4096][K]
    const float* __restrict__ bih,  // [4096]
    const float* __restrict__ bhh,  // [4096]
    u16* __restrict__ out,          // [1024][4096] bf16
    int K)
{
    __shared__ u16 As[128][40];
    __shared__ u16 Bs[128][40];
    const int tm = blockIdx.x;       // 0..7
    const int tn = blockIdx.y;       // 0..31
    const int tid = threadIdx.x;
    const int lane = tid & 63;
    const int wv = tid >> 6;
    const int wm = wv >> 1, wn = wv & 1;
    const int fr = lane & 15, fq = lane >> 4;

    v4f acc[4][4] = {};

    for (int kt = 0; kt < K; kt += 32) {
#pragma unroll
        for (int it = 0; it < 2; ++it) {
            int q = tid + it * 256;          // 0..511
            int r = q >> 2;
            int c8 = (q & 3) * 8;
            const float* pa = &A[(size_t)(tm * 128 + r) * K + kt + c8];
            const float* pw = &W[(size_t)(tn * 128 + r) * K + kt + c8];
            *(v8s*)&As[r][c8] = pack8(*(const v4f*)pa, *(const v4f*)(pa + 4));
            *(v8s*)&Bs[r][c8] = pack8(*(const v4f*)pw, *(const v4f*)(pw + 4));
        }
        __syncthreads();
        v8s af[4], bfr[4];
#pragma unroll
        for (int mi = 0; mi < 4; ++mi)
            af[mi] = *(const v8s*)&As[wm * 64 + mi * 16 + fr][fq * 8];
#pragma unroll
        for (int ni = 0; ni < 4; ++ni)
            bfr[ni] = *(const v8s*)&Bs[wn * 64 + ni * 16 + fr][fq * 8];
#pragma unroll
        for (int mi = 0; mi < 4; ++mi)
#pragma unroll
            for (int ni = 0; ni < 4; ++ni)
                acc[mi][ni] = __builtin_amdgcn_mfma_f32_16x16x32_bf16(af[mi], bfr[ni], acc[mi][ni], 0, 0, 0);
        __syncthreads();
    }

#pragma unroll
    for (int ni = 0; ni < 4; ++ni) {
        int col = tn * 128 + wn * 64 + ni * 16 + fr;
        float bias = bih[col] + bhh[col];
#pragma unroll
        for (int mi = 0; mi < 4; ++mi) {
#pragma unroll
            for (int j = 0; j < 4; ++j) {
                int row = tm * 128 + wm * 64 + mi * 16 + fq * 4 + j;
                out[(size_t)row * 4096 + col] = f2bf(acc[mi][ni][j] + bias);
            }
        }
    }
}

// ---------------------------------------------------------------------------
// Persistent LSTM scan, one layer, both directions.
// 256 WGs: d = bid>>7, wg = bid&127. WG owns h elements e0..e0+7, i.e. Whh
// rows {g*1024 + e0+ei}, g=0..3 (i,f,g,o), held as bf16 in LDS (64 KiB).
// h is fp32; broadcast via agent-scope atomics into hseq + per-WG flag.
// ---------------------------------------------------------------------------
__global__ __launch_bounds__(256, 1) void lstm_scan(
    const float* __restrict__ Whh_fw,  // [4096][1024] fp32
    const float* __restrict__ Whh_bw,
    const u16* __restrict__ precomp,   // [2][1024][4096] bf16
    float* hseq,                       // [2][1024][1024] fp32
    int* flags,                        // [2][128]
    float* cm_out,                     // final c -> d_out row (2048 floats)
    float* hs_out,                     // final h
    float* seq_out,                    // layer1: [1024][2048] fp32, else null
    int rev)                           // layer0: bw indexes precomp at 1023-s
{
    extern __shared__ char smem[];
    float* h_sh      = (float*)(smem + 65536);  // 1280 floats (pad 2 per 8)
    float* gates_lds = h_sh + 1280;             // 32
    float* c_lds     = gates_lds + 32;          // 8

    const int tid = threadIdx.x;
    const int lane = tid & 63;
    const int w = tid >> 6;
    const int bid = blockIdx.x;
    const int d = bid >> 7;
    const int wg = bid & 127;
    const int e0 = wg << 3;
    const float* __restrict__ Whh = d ? Whh_bw : Whh_fw;
    int* myflags = flags + d * 128;
    float* hbase = hseq + (size_t)d * 1024 * 1024;

    // Preload 32x1024 fp32 Whh slice -> bf16 LDS, layout [gate][ei][1024].
#pragma unroll
    for (int it = 0; it < 16; ++it) {
        int q = tid + (it << 8);            // 0..4095, 8 elems each
        int g = q >> 10;
        int ei = (q >> 7) & 7;
        int cc = (q & 127) << 3;
        const float* pw = &Whh[(size_t)(g * 1024 + e0 + ei) * 1024 + cc];
        *(v8s*)(smem + (size_t)q * 16) = pack8(*(const v4f*)pw, *(const v4f*)(pw + 4));
    }
    if (tid < 8) c_lds[tid] = 0.0f;
    __syncthreads();

    const char* wbase = smem + w * 16384 + lane * 16;

    for (int s = 0; s < 1024; ++s) {
        float acc[8] = {0, 0, 0, 0, 0, 0, 0, 0};
        if (s > 0) {
            if (tid < 64) {
                for (;;) {
                    int a = __hip_atomic_load(&myflags[tid], __ATOMIC_ACQUIRE, __HIP_MEMORY_SCOPE_AGENT);
                    int b = __hip_atomic_load(&myflags[tid + 64], __ATOMIC_ACQUIRE, __HIP_MEMORY_SCOPE_AGENT);
                    if (a >= s && b >= s) break;
                    __builtin_amdgcn_s_sleep(2);
                }
            }
            __syncthreads();

            // Stage h[s-1] (1024 fp32) into padded LDS: idx' = i + (i>>3)*2.
            u32* hrow = (u32*)(hbase + (size_t)(s - 1) * 1024);
#pragma unroll
            for (int k2 = 0; k2 < 4; ++k2) {
                int i = tid + (k2 << 8);
                u32 v = __hip_atomic_load(&hrow[i], __ATOMIC_RELAXED, __HIP_MEMORY_SCOPE_AGENT);
                h_sh[i + ((i >> 3) << 1)] = __uint_as_float(v);
            }
            __syncthreads();

            float hh[16];
            const float* g0 = &h_sh[lane * 10];        // cols lane*8..+7
            const float* g1 = &h_sh[640 + lane * 10];  // cols 512+lane*8..+7
#pragma unroll
            for (int j2 = 0; j2 < 4; ++j2) {
                *(v2f*)&hh[j2 * 2]     = *(const v2f*)&g0[j2 * 2];
                *(v2f*)&hh[8 + j2 * 2] = *(const v2f*)&g1[j2 * 2];
            }

            // instr i: 16B of weights at wbase + i*1024 ->
            // row r=i>>1 of this wave's gate, cols (i&1)*512 + lane*8 .. +8
#pragma unroll
            for (int i = 0; i < 16; ++i) {
                v4u wv4 = *(const v4u*)(wbase + i * 1024);
                const int r = i >> 1;
                const float* hp = &hh[(i & 1) * 8];
                acc[r] = fmaf(blo(wv4[0]), hp[0], acc[r]);
                acc[r] = fmaf(bhi(wv4[0]), hp[1], acc[r]);
                acc[r] = fmaf(blo(wv4[1]), hp[2], acc[r]);
                acc[r] = fmaf(bhi(wv4[1]), hp[3], acc[r]);
                acc[r] = fmaf(blo(wv4[2]), hp[4], acc[r]);
                acc[r] = fmaf(bhi(wv4[2]), hp[5], acc[r]);
                acc[r] = fmaf(blo(wv4[3]), hp[6], acc[r]);
                acc[r] = fmaf(bhi(wv4[3]), hp[7], acc[r]);
            }
        }
        // wave-reduce 8 rows; lane0 publishes (wave w <-> gate w)
#pragma unroll
        for (int r = 0; r < 8; ++r) {
            float v = acc[r];
#pragma unroll
            for (int off = 32; off > 0; off >>= 1) v += __shfl_xor(v, off, 64);
            if (lane == 0) gates_lds[w * 8 + r] = v;
        }
        __syncthreads();

        if (tid < 8) {
            int sx = (rev && d) ? (1023 - s) : s;
            const u16* pr = precomp + ((size_t)d * 1024 + sx) * 4096 + e0 + tid;
            float Gi = gates_lds[tid]      + bf2f(pr[0]);
            float Gf = gates_lds[8 + tid]  + bf2f(pr[1024]);
            float Gg = gates_lds[16 + tid] + bf2f(pr[2048]);
            float Go = gates_lds[24 + tid] + bf2f(pr[3072]);
            float c = sigf(Gf) * c_lds[tid] + sigf(Gi) * tanhf(Gg);
            float h = sigf(Go) * tanhf(c);
            c_lds[tid] = c;
            __hip_atomic_store((u32*)&hbase[(size_t)s * 1024 + e0 + tid],
                               __float_as_uint(h), __ATOMIC_RELAXED, __HIP_MEMORY_SCOPE_AGENT);
            if (seq_out) {
                int row = d ? (1023 - s) : s;
                seq_out[(size_t)row * 2048 + d * 1024 + e0 + tid] = h;
            }
            if (s == 1023) {
                cm_out[d * 1024 + e0 + tid] = c;
                hs_out[d * 1024 + e0 + tid] = h;
            }
        }
        if (tid == 0) {
            __threadfence();
            __hip_atomic_store(&myflags[wg], s + 1, __ATOMIC_RELEASE, __HIP_MEMORY_SCOPE_AGENT);
        }
    }
}

// ---------------------------------------------------------------------------
extern "C" void kernel_launch(void* const* d_in, const int* in_sizes, int n_in,
                              void* d_out, int out_size, void* d_ws, size_t ws_size,
                              hipStream_t stream) {
    (void)in_sizes; (void)n_in; (void)out_size; (void)ws_size;

    const float* x       = (const float*)d_in[0];
    const float* fw0_Wih = (const float*)d_in[1];
    const float* fw0_Whh = (const float*)d_in[2];
    const float* fw0_bih = (const float*)d_in[3];
    const float* fw0_bhh = (const float*)d_in[4];
    const float* fw1_Wih = (const float*)d_in[5];
    const float* fw1_Whh = (const float*)d_in[6];
    const float* fw1_bih = (const float*)d_in[7];
    const float* fw1_bhh = (const float*)d_in[8];
    const float* bw0_Wih = (const float*)d_in[9];
    const float* bw0_Whh = (const float*)d_in[10];
    const float* bw0_bih = (const float*)d_in[11];
    const float* bw0_bhh = (const float*)d_in[12];
    const float* bw1_Wih = (const float*)d_in[13];
    const float* bw1_Whh = (const float*)d_in[14];
    const float* bw1_bih = (const float*)d_in[15];
    const float* bw1_bhh = (const float*)d_in[16];

    char* ws = (char*)d_ws;
    u16*   precomp = (u16*)ws;                        // [2][1024][4096] bf16 = 16 MB
    float* hseq    = (float*)(ws + (16 << 20));       // [2][1024][1024] fp32 =  8 MB
    int*   flags   = (int*)(ws + (24 << 20));         // [2 layers][2][128]   =  2 KB
    float* out     = (float*)d_out;

    hipMemsetAsync(flags, 0, 512 * sizeof(int), stream);

    dim3 g(8, 32);
    // Phase 1: layer-0 input projections (bw uses same x; scan reverses index).
    gemm_ih<<<g, 256, 0, stream>>>(x, fw0_Wih, fw0_bih, fw0_bhh, precomp, 768);
    gemm_ih<<<g, 256, 0, stream>>>(x, bw0_Wih, bw0_bih, bw0_bhh, precomp + (size_t)1024 * 4096, 768);
    // Phase 2: scan layer 0 (h0 sequence -> hseq, finals -> d_out rows 0).
    lstm_scan<<<256, 256, 71680, stream>>>(fw0_Whh, bw0_Whh, precomp, hseq, flags,
                                           out, out + 4096, (float*)nullptr, 1);
    // Phase 3: layer-1 input projections from h0 sequences (scan order).
    gemm_ih<<<g, 256, 0, stream>>>(hseq, fw1_Wih, fw1_bih, fw1_bhh, precomp, 1024);
    gemm_ih<<<g, 256, 0, stream>>>(hseq + (size_t)1024 * 1024, bw1_Wih, bw1_bih, bw1_bhh,
                                   precomp + (size_t)1024 * 4096, 1024);
    // Phase 4: scan layer 1 (finals -> d_out rows 1, sequence -> final_outputs).
    lstm_scan<<<256, 256, 71680, stream>>>(fw1_Whh, bw1_Whh, precomp, hseq, flags + 256,
                                           out + 2048, out + 4096 + 2048, out + 8192, 0);
}

// Round 3
// 8848.816 us; speedup vs baseline: 4.2173x; 4.2173x over previous
//
#include <hip/hip_runtime.h>

typedef unsigned int u32;
typedef unsigned short u16;
typedef unsigned long long u64;
typedef __attribute__((ext_vector_type(8))) short v8s;   // 8 bf16
typedef __attribute__((ext_vector_type(4))) float v4f;
typedef __attribute__((ext_vector_type(2))) float v2f;
typedef __attribute__((ext_vector_type(4))) u32 v4u;

__device__ __forceinline__ float bf2f(u16 v) { return __uint_as_float(((u32)v) << 16); }
__device__ __forceinline__ u16 f2bf(float f) {
    u32 u = __float_as_uint(f);
    return (u16)((u + 0x7fffu + ((u >> 16) & 1u)) >> 16);   // RNE
}
__device__ __forceinline__ float blo(u32 u) { return __uint_as_float(u << 16); }
__device__ __forceinline__ float bhi(u32 u) { return __uint_as_float(u & 0xffff0000u); }
__device__ __forceinline__ float sigf(float x) { return 1.0f / (1.0f + __expf(-x)); }
__device__ __forceinline__ v8s pack8(v4f a, v4f b) {
    v8s r;
    r[0] = (short)f2bf(a[0]); r[1] = (short)f2bf(a[1]);
    r[2] = (short)f2bf(a[2]); r[3] = (short)f2bf(a[3]);
    r[4] = (short)f2bf(b[0]); r[5] = (short)f2bf(b[1]);
    r[6] = (short)f2bf(b[2]); r[7] = (short)f2bf(b[3]);
    return r;
}

// ---------------------------------------------------------------------------
// GEMM: out[t][j] = sum_k A[t][k]*W[j][k] + bih[j] + bhh[j].
// A,W,b fp32 in; out bf16 (precomp). M=1024, N=4096, K in {768,1024}.
// ---------------------------------------------------------------------------
__global__ __launch_bounds__(256) void gemm_ih(
    const float* __restrict__ A,    // [1024][K]
    const float* __restrict__ W,    // [4096][K]
    const float* __restrict__ bih,  // [4096]
    const float* __restrict__ bhh,  // [4096]
    u16* __restrict__ out,          // [1024][4096] bf16
    int K)
{
    __shared__ u16 As[128][40];
    __shared__ u16 Bs[128][40];
    const int tm = blockIdx.x;       // 0..7
    const int tn = blockIdx.y;       // 0..31
    const int tid = threadIdx.x;
    const int lane = tid & 63;
    const int wv = tid >> 6;
    const int wm = wv >> 1, wn = wv & 1;
    const int fr = lane & 15, fq = lane >> 4;

    v4f acc[4][4] = {};

    for (int kt = 0; kt < K; kt += 32) {
#pragma unroll
        for (int it = 0; it < 2; ++it) {
            int q = tid + it * 256;          // 0..511
            int r = q >> 2;
            int c8 = (q & 3) * 8;
            const float* pa = &A[(size_t)(tm * 128 + r) * K + kt + c8];
            const float* pw = &W[(size_t)(tn * 128 + r) * K + kt + c8];
            *(v8s*)&As[r][c8] = pack8(*(const v4f*)pa, *(const v4f*)(pa + 4));
            *(v8s*)&Bs[r][c8] = pack8(*(const v4f*)pw, *(const v4f*)(pw + 4));
        }
        __syncthreads();
        v8s af[4], bfr[4];
#pragma unroll
        for (int mi = 0; mi < 4; ++mi)
            af[mi] = *(const v8s*)&As[wm * 64 + mi * 16 + fr][fq * 8];
#pragma unroll
        for (int ni = 0; ni < 4; ++ni)
            bfr[ni] = *(const v8s*)&Bs[wn * 64 + ni * 16 + fr][fq * 8];
#pragma unroll
        for (int mi = 0; mi < 4; ++mi)
#pragma unroll
            for (int ni = 0; ni < 4; ++ni)
                acc[mi][ni] = __builtin_amdgcn_mfma_f32_16x16x32_bf16(af[mi], bfr[ni], acc[mi][ni], 0, 0, 0);
        __syncthreads();
    }

#pragma unroll
    for (int ni = 0; ni < 4; ++ni) {
        int col = tn * 128 + wn * 64 + ni * 16 + fr;
        float bias = bih[col] + bhh[col];
#pragma unroll
        for (int mi = 0; mi < 4; ++mi) {
#pragma unroll
            for (int j = 0; j < 4; ++j) {
                int row = tm * 128 + wm * 64 + mi * 16 + fq * 4 + j;
                out[(size_t)row * 4096 + col] = f2bf(acc[mi][ni][j] + bias);
            }
        }
    }
}

// ---------------------------------------------------------------------------
// Persistent LSTM scan, one layer, both directions.
// 256 WGs: d = bid>>7, wg = bid&127. WG owns h elements e0..e0+7 (Whh rows
// {g*1024+e0+ei}, g=0..3 i,f,g,o), bf16 in LDS (64 KiB).
// h broadcast: self-validating tagged words. htag[d][s][w] (u64) =
// ((tagbase+s+1)<<32) | (bf16 h[2w+1] <<16 | bf16 h[2w]). Relaxed agent
// atomics only — data and tag are one atomic word, so no fences/flags.
// ---------------------------------------------------------------------------
__global__ __launch_bounds__(256, 1) void lstm_scan(
    const float* __restrict__ Whh_fw,  // [4096][1024] fp32
    const float* __restrict__ Whh_bw,
    const u16* __restrict__ precomp,   // [2][1024][4096] bf16
    u64* htag,                         // [2][1024][512]
    float* hplain,                     // [2][1024][1024] fp32 (layer0) or null
    float* cm_out,                     // final c -> d_out (2048 floats)
    float* hs_out,                     // final h
    float* seq_out,                    // layer1: [1024][2048] fp32, else null
    int rev,                           // layer0: bw indexes precomp at 1023-s
    u32 tagbase)                       // 0 for layer0, 4096 for layer1
{
    extern __shared__ char smem[];
    float* h_sh      = (float*)(smem + 65536);  // 1280 floats (pad 2 per 8)
    float* gates_lds = h_sh + 1280;             // 32
    float* c_lds     = gates_lds + 32;          // 8
    float* h_lds     = c_lds + 8;               // 8

    const int tid = threadIdx.x;
    const int lane = tid & 63;
    const int w = tid >> 6;
    const int bid = blockIdx.x;
    const int d = bid >> 7;
    const int wg = bid & 127;
    const int e0 = wg << 3;
    const float* __restrict__ Whh = d ? Whh_bw : Whh_fw;
    u64* hbase = htag + (size_t)d * 1024 * 512;

    // Preload 32x1024 fp32 Whh slice -> bf16 LDS, layout [gate][ei][1024].
#pragma unroll
    for (int it = 0; it < 16; ++it) {
        int q = tid + (it << 8);            // 0..4095, 8 elems each
        int g = q >> 10;
        int ei = (q >> 7) & 7;
        int cc = (q & 127) << 3;
        const float* pw = &Whh[(size_t)(g * 1024 + e0 + ei) * 1024 + cc];
        *(v8s*)(smem + (size_t)q * 16) = pack8(*(const v4f*)pw, *(const v4f*)(pw + 4));
    }
    if (tid < 8) c_lds[tid] = 0.0f;
    __syncthreads();

    const char* wbase = smem + w * 16384 + lane * 16;

    for (int s = 0; s < 1024; ++s) {
        float acc[8] = {0, 0, 0, 0, 0, 0, 0, 0};
        if (s > 0) {
            // Poll h[s-1]: thread t owns words 2t, 2t+1 (elements 4t..4t+3).
            const u32 want = tagbase + (u32)s;
            u64* row = hbase + (size_t)(s - 1) * 512 + tid * 2;
            u64 w0, w1;
            for (;;) {
                w0 = __hip_atomic_load(&row[0], __ATOMIC_RELAXED, __HIP_MEMORY_SCOPE_AGENT);
                w1 = __hip_atomic_load(&row[1], __ATOMIC_RELAXED, __HIP_MEMORY_SCOPE_AGENT);
                if ((u32)(w0 >> 32) == want && (u32)(w1 >> 32) == want) break;
                __builtin_amdgcn_s_sleep(1);
            }
            int e = tid << 2;
            int ip = e + ((e >> 3) << 1);   // padded index (stride 10 per 8)
            v2f a; a[0] = blo((u32)w0); a[1] = bhi((u32)w0);
            v2f b; b[0] = blo((u32)w1); b[1] = bhi((u32)w1);
            *(v2f*)&h_sh[ip]     = a;
            *(v2f*)&h_sh[ip + 2] = b;
            __syncthreads();

            float hh[16];
            const float* g0 = &h_sh[lane * 10];        // cols lane*8..+7
            const float* g1 = &h_sh[640 + lane * 10];  // cols 512+lane*8..+7
#pragma unroll
            for (int j2 = 0; j2 < 4; ++j2) {
                *(v2f*)&hh[j2 * 2]     = *(const v2f*)&g0[j2 * 2];
                *(v2f*)&hh[8 + j2 * 2] = *(const v2f*)&g1[j2 * 2];
            }

            // instr i: 16B of weights at wbase + i*1024 ->
            // row r=i>>1 of this wave's gate, cols (i&1)*512 + lane*8 .. +8
#pragma unroll
            for (int i = 0; i < 16; ++i) {
                v4u wv4 = *(const v4u*)(wbase + i * 1024);
                const int r = i >> 1;
                const float* hp = &hh[(i & 1) * 8];
                acc[r] = fmaf(blo(wv4[0]), hp[0], acc[r]);
                acc[r] = fmaf(bhi(wv4[0]), hp[1], acc[r]);
                acc[r] = fmaf(blo(wv4[1]), hp[2], acc[r]);
                acc[r] = fmaf(bhi(wv4[1]), hp[3], acc[r]);
                acc[r] = fmaf(blo(wv4[2]), hp[4], acc[r]);
                acc[r] = fmaf(bhi(wv4[2]), hp[5], acc[r]);
                acc[r] = fmaf(blo(wv4[3]), hp[6], acc[r]);
                acc[r] = fmaf(bhi(wv4[3]), hp[7], acc[r]);
            }
        }
        // wave-reduce 8 rows; lane0 publishes (wave w <-> gate w)
#pragma unroll
        for (int r = 0; r < 8; ++r) {
            float v = acc[r];
#pragma unroll
            for (int off = 32; off > 0; off >>= 1) v += __shfl_xor(v, off, 64);
            if (lane == 0) gates_lds[w * 8 + r] = v;
        }
        __syncthreads();

        if (tid < 8) {
            int sx = (rev && d) ? (1023 - s) : s;
            const u16* pr = precomp + ((size_t)d * 1024 + sx) * 4096 + e0 + tid;
            float Gi = gates_lds[tid]      + bf2f(pr[0]);
            float Gf = gates_lds[8 + tid]  + bf2f(pr[1024]);
            float Gg = gates_lds[16 + tid] + bf2f(pr[2048]);
            float Go = gates_lds[24 + tid] + bf2f(pr[3072]);
            float c = sigf(Gf) * c_lds[tid] + sigf(Gi) * tanhf(Gg);
            float h = sigf(Go) * tanhf(c);
            c_lds[tid] = c;
            h_lds[tid] = h;
        }
        // Critical-path publish first (same wave as tid<8 -> LDS RAW ordered).
        if (tid < 4) {
            u32 pk = (u32)f2bf(h_lds[2 * tid]) | ((u32)f2bf(h_lds[2 * tid + 1]) << 16);
            u64 val = ((u64)(tagbase + (u32)s + 1u) << 32) | pk;
            __hip_atomic_store(&hbase[(size_t)s * 512 + (e0 >> 1) + tid], val,
                               __ATOMIC_RELAXED, __HIP_MEMORY_SCOPE_AGENT);
        }
        // Non-critical plain stores (consumed after kernel boundary).
        if (tid < 8) {
            float h = h_lds[tid];
            if (hplain)
                hplain[(size_t)d * 1024 * 1024 + (size_t)s * 1024 + e0 + tid] = h;
            if (seq_out) {
                int rrow = d ? (1023 - s) : s;
                seq_out[(size_t)rrow * 2048 + d * 1024 + e0 + tid] = h;
            }
            if (s == 1023) {
                cm_out[d * 1024 + e0 + tid] = c_lds[tid];
                hs_out[d * 1024 + e0 + tid] = h;
            }
        }
    }
}

// ---------------------------------------------------------------------------
extern "C" void kernel_launch(void* const* d_in, const int* in_sizes, int n_in,
                              void* d_out, int out_size, void* d_ws, size_t ws_size,
                              hipStream_t stream) {
    (void)in_sizes; (void)n_in; (void)out_size; (void)ws_size;

    const float* x       = (const float*)d_in[0];
    const float* fw0_Wih = (const float*)d_in[1];
    const float* fw0_Whh = (const float*)d_in[2];
    const float* fw0_bih = (const float*)d_in[3];
    const float* fw0_bhh = (const float*)d_in[4];
    const float* fw1_Wih = (const float*)d_in[5];
    const float* fw1_Whh = (const float*)d_in[6];
    const float* fw1_bih = (const float*)d_in[7];
    const float* fw1_bhh = (const float*)d_in[8];
    const float* bw0_Wih = (const float*)d_in[9];
    const float* bw0_Whh = (const float*)d_in[10];
    const float* bw0_bih = (const float*)d_in[11];
    const float* bw0_bhh = (const float*)d_in[12];
    const float* bw1_Wih = (const float*)d_in[13];
    const float* bw1_Whh = (const float*)d_in[14];
    const float* bw1_bih = (const float*)d_in[15];
    const float* bw1_bhh = (const float*)d_in[16];

    char* ws = (char*)d_ws;
    u16*   precomp = (u16*)ws;                        // [2][1024][4096] bf16 = 16 MB
    float* hplain  = (float*)(ws + (16 << 20));       // [2][1024][1024] fp32 =  8 MB
    u64*   htag    = (u64*)(ws + (24 << 20));         // [2][1024][512] u64   =  8 MB
    float* out     = (float*)d_out;

    hipMemsetAsync(htag, 0, (size_t)8 << 20, stream);

    dim3 g(8, 32);
    // Phase 1: layer-0 input projections (bw uses same x; scan reverses index).
    gemm_ih<<<g, 256, 0, stream>>>(x, fw0_Wih, fw0_bih, fw0_bhh, precomp, 768);
    gemm_ih<<<g, 256, 0, stream>>>(x, bw0_Wih, bw0_bih, bw0_bhh, precomp + (size_t)1024 * 4096, 768);
    // Phase 2: scan layer 0 (h0 sequence -> hplain/htag, finals -> d_out rows 0).
    lstm_scan<<<256, 256, 71168, stream>>>(fw0_Whh, bw0_Whh, precomp, htag, hplain,
                                           out, out + 4096, (float*)nullptr, 1, 0u);
    // Phase 3: layer-1 input projections from h0 sequences (scan order).
    gemm_ih<<<g, 256, 0, stream>>>(hplain, fw1_Wih, fw1_bih, fw1_bhh, precomp, 1024);
    gemm_ih<<<g, 256, 0, stream>>>(hplain + (size_t)1024 * 1024, bw1_Wih, bw1_bih, bw1_bhh,
                                   precomp + (size_t)1024 * 4096, 1024);
    // Phase 4: scan layer 1 (finals -> d_out rows 1, sequence -> final_outputs).
    lstm_scan<<<256, 256, 71168, stream>>>(fw1_Whh, bw1_Whh, precomp, htag, (float*)nullptr,
                                           out + 2048, out + 4096 + 2048, out + 8192, 0, 4096u);
}

// Round 4
// 5555.113 us; speedup vs baseline: 6.7178x; 1.5929x over previous
//
#include <hip/hip_runtime.h>

typedef unsigned int u32;
typedef unsigned short u16;
typedef unsigned long long u64;
typedef __attribute__((ext_vector_type(8))) short v8s;   // 8 bf16
typedef __attribute__((ext_vector_type(4))) float v4f;
typedef __attribute__((ext_vector_type(2))) float v2f;
typedef __attribute__((ext_vector_type(4))) u32 v4u;

__device__ __forceinline__ float bf2f(u16 v) { return __uint_as_float(((u32)v) << 16); }
__device__ __forceinline__ u16 f2bf(float f) {
    u32 u = __float_as_uint(f);
    return (u16)((u + 0x7fffu + ((u >> 16) & 1u)) >> 16);   // RNE
}
__device__ __forceinline__ float blo(u32 u) { return __uint_as_float(u << 16); }
__device__ __forceinline__ float bhi(u32 u) { return __uint_as_float(u & 0xffff0000u); }
__device__ __forceinline__ float sigf(float x) { return 1.0f / (1.0f + __expf(-x)); }
__device__ __forceinline__ float tanhfast(float x) {
    float e = __expf(2.0f * x);          // inf for large x -> 1; 0 for very neg -> -1
    return 1.0f - 2.0f / (e + 1.0f);
}
__device__ __forceinline__ v8s pack8(v4f a, v4f b) {
    v8s r;
    r[0] = (short)f2bf(a[0]); r[1] = (short)f2bf(a[1]);
    r[2] = (short)f2bf(a[2]); r[3] = (short)f2bf(a[3]);
    r[4] = (short)f2bf(b[0]); r[5] = (short)f2bf(b[1]);
    r[6] = (short)f2bf(b[2]); r[7] = (short)f2bf(b[3]);
    return r;
}

// ---------------------------------------------------------------------------
// GEMM: out[t][j] = sum_k A[t][k]*W[j][k] + bih[j] + bhh[j]. fp32 in, bf16 out.
// Used only for layer-0 input projections (K=768).
// ---------------------------------------------------------------------------
__global__ __launch_bounds__(256) void gemm_ih(
    const float* __restrict__ A, const float* __restrict__ W,
    const float* __restrict__ bih, const float* __restrict__ bhh,
    u16* __restrict__ out, int K)
{
    __shared__ u16 As[128][40];
    __shared__ u16 Bs[128][40];
    const int tm = blockIdx.x, tn = blockIdx.y;
    const int tid = threadIdx.x;
    const int lane = tid & 63;
    const int wv = tid >> 6;
    const int wm = wv >> 1, wn = wv & 1;
    const int fr = lane & 15, fq = lane >> 4;

    v4f acc[4][4] = {};

    for (int kt = 0; kt < K; kt += 32) {
#pragma unroll
        for (int it = 0; it < 2; ++it) {
            int q = tid + it * 256;
            int r = q >> 2;
            int c8 = (q & 3) * 8;
            const float* pa = &A[(size_t)(tm * 128 + r) * K + kt + c8];
            const float* pw = &W[(size_t)(tn * 128 + r) * K + kt + c8];
            *(v8s*)&As[r][c8] = pack8(*(const v4f*)pa, *(const v4f*)(pa + 4));
            *(v8s*)&Bs[r][c8] = pack8(*(const v4f*)pw, *(const v4f*)(pw + 4));
        }
        __syncthreads();
        v8s af[4], bfr[4];
#pragma unroll
        for (int mi = 0; mi < 4; ++mi)
            af[mi] = *(const v8s*)&As[wm * 64 + mi * 16 + fr][fq * 8];
#pragma unroll
        for (int ni = 0; ni < 4; ++ni)
            bfr[ni] = *(const v8s*)&Bs[wn * 64 + ni * 16 + fr][fq * 8];
#pragma unroll
        for (int mi = 0; mi < 4; ++mi)
#pragma unroll
            for (int ni = 0; ni < 4; ++ni)
                acc[mi][ni] = __builtin_amdgcn_mfma_f32_16x16x32_bf16(af[mi], bfr[ni], acc[mi][ni], 0, 0, 0);
        __syncthreads();
    }

#pragma unroll
    for (int ni = 0; ni < 4; ++ni) {
        int col = tn * 128 + wn * 64 + ni * 16 + fr;
        float bias = bih[col] + bhh[col];
#pragma unroll
        for (int mi = 0; mi < 4; ++mi)
#pragma unroll
            for (int j = 0; j < 4; ++j) {
                int row = tm * 128 + wm * 64 + mi * 16 + fq * 4 + j;
                out[(size_t)row * 4096 + col] = f2bf(acc[mi][ni][j] + bias);
            }
    }
}

// ---------------------------------------------------------------------------
// Fused persistent bidirectional 2-layer LSTM scan.
// 512 WGs, 2/CU: role = bid>>8 (0: layer0, 1: layer1), d = (bid>>7)&1,
// wg = bid&127, e0 = wg*8. Each WG owns 8 h-elements (32 Whh rows, bf16 LDS).
// Layer-1 WGs additionally hold their 32 Wih1 rows in REGISTERS (wbuf[16])
// and consume h0 directly from layer-0's tagged broadcast, eliminating the
// interlayer GEMM. h broadcast: u64 = (tag s+1)<<32 | 2xbf16, relaxed agent
// atomics, separate buffers per layer (memset to 0 each launch).
// ---------------------------------------------------------------------------
__global__ __launch_bounds__(256, 2) void lstm_fused(
    const float* __restrict__ fw0_Whh, const float* __restrict__ bw0_Whh,
    const float* __restrict__ fw1_Whh, const float* __restrict__ bw1_Whh,
    const float* __restrict__ fw1_Wih, const float* __restrict__ bw1_Wih,
    const float* __restrict__ fw1_bih, const float* __restrict__ fw1_bhh,
    const float* __restrict__ bw1_bih, const float* __restrict__ bw1_bhh,
    const u16*  __restrict__ precomp0,   // [2][1024][4096] bf16
    u64* htag0,                          // [2][1024][512]
    u64* htag1,                          // [2][1024][512]
    float* __restrict__ out)             // d_out base
{
    extern __shared__ char smem[];
    float* hA_sh     = (float*)(smem + 65536);  // 1280 (own-layer h)
    float* hB_sh     = hA_sh + 1280;            // 1280 (h0 input, L1 only)
    float* gates_lds = hB_sh + 1280;            // 32
    float* c_lds     = gates_lds + 32;          // 8
    float* h_lds     = c_lds + 8;               // 8
    float* bias_lds  = h_lds + 8;               // 32

    const int tid = threadIdx.x;
    const int lane = tid & 63;
    const int w = tid >> 6;
    const int bid = blockIdx.x;
    const int role = bid >> 8;          // 0 = layer0, 1 = layer1
    const int sub = bid & 255;
    const int d = sub >> 7;
    const int wg = sub & 127;
    const int e0 = wg << 3;

    const float* __restrict__ Whh =
        role ? (d ? bw1_Whh : fw1_Whh) : (d ? bw0_Whh : fw0_Whh);

    // Whh slice (32 rows x 1024) fp32 -> bf16 LDS, layout [gate][ei][1024].
#pragma unroll
    for (int it = 0; it < 16; ++it) {
        int q = tid + (it << 8);
        int g = q >> 10, ei = (q >> 7) & 7, cc = (q & 127) << 3;
        const float* pw = &Whh[(size_t)(g * 1024 + e0 + ei) * 1024 + cc];
        *(v8s*)(smem + (size_t)q * 16) = pack8(*(const v4f*)pw, *(const v4f*)(pw + 4));
    }

    // Layer-1: Wih1 slice -> registers (64 VGPR/lane), biases -> LDS.
    v4u wbuf[16];
    if (role) {
        const float* __restrict__ Wih = d ? bw1_Wih : fw1_Wih;
#pragma unroll
        for (int i = 0; i < 16; ++i) {
            int ei = i >> 1, c0 = ((i & 1) << 9) + (lane << 3);
            const float* p = &Wih[(size_t)(w * 1024 + e0 + ei) * 1024 + c0];
            v8s t = pack8(*(const v4f*)p, *(const v4f*)(p + 4));
            wbuf[i] = *(v4u*)&t;
        }
        if (tid < 32) {
            const float* bi = d ? bw1_bih : fw1_bih;
            const float* bh = d ? bw1_bhh : fw1_bhh;
            int g = tid >> 3, e = tid & 7;
            bias_lds[tid] = bi[g * 1024 + e0 + e] + bh[g * 1024 + e0 + e];
        }
    }
    if (tid < 8) c_lds[tid] = 0.0f;
    __syncthreads();

    const char* wbase = smem + w * 16384 + lane * 16;
    u64* hown = (role ? htag1 : htag0) + (size_t)d * 1024 * 512;
    u64* hin  = htag0 + (size_t)d * 1024 * 512;

    float* cm_out = out + role * 2048;
    float* hs_out = out + 4096 + role * 2048;
    float* seq_out = out + 8192;    // [1024][2048], written by role 1

    if (role == 0) {
        // ------------------------- layer 0 scan -------------------------
        for (int s = 0; s < 1024; ++s) {
            float acc[8] = {0, 0, 0, 0, 0, 0, 0, 0};
            if (s > 0) {
                const u32 want = (u32)s;
                u64* row = hown + (size_t)(s - 1) * 512 + tid * 2;
                u64 w0, w1;
                for (;;) {
                    w0 = __hip_atomic_load(&row[0], __ATOMIC_RELAXED, __HIP_MEMORY_SCOPE_AGENT);
                    w1 = __hip_atomic_load(&row[1], __ATOMIC_RELAXED, __HIP_MEMORY_SCOPE_AGENT);
                    if ((u32)(w0 >> 32) == want && (u32)(w1 >> 32) == want) break;
                    __builtin_amdgcn_s_sleep(1);
                }
                int e = tid << 2;
                int ip = e + ((e >> 3) << 1);
                h_lds_stage:
                hA_sh[ip]     = blo((u32)w0); hA_sh[ip + 1] = bhi((u32)w0);
                hA_sh[ip + 2] = blo((u32)w1); hA_sh[ip + 3] = bhi((u32)w1);
                __syncthreads();

                float hh[16];
                const float* g0 = &hA_sh[lane * 10];
                const float* g1 = &hA_sh[640 + lane * 10];
#pragma unroll
                for (int j2 = 0; j2 < 4; ++j2) {
                    *(v2f*)&hh[j2 * 2]     = *(const v2f*)&g0[j2 * 2];
                    *(v2f*)&hh[8 + j2 * 2] = *(const v2f*)&g1[j2 * 2];
                }
#pragma unroll
                for (int i = 0; i < 16; ++i) {
                    v4u wv4 = *(const v4u*)(wbase + i * 1024);
                    const int r = i >> 1;
                    const float* hp = &hh[(i & 1) * 8];
                    acc[r] = fmaf(blo(wv4[0]), hp[0], acc[r]);
                    acc[r] = fmaf(bhi(wv4[0]), hp[1], acc[r]);
                    acc[r] = fmaf(blo(wv4[1]), hp[2], acc[r]);
                    acc[r] = fmaf(bhi(wv4[1]), hp[3], acc[r]);
                    acc[r] = fmaf(blo(wv4[2]), hp[4], acc[r]);
                    acc[r] = fmaf(bhi(wv4[2]), hp[5], acc[r]);
                    acc[r] = fmaf(blo(wv4[3]), hp[6], acc[r]);
                    acc[r] = fmaf(bhi(wv4[3]), hp[7], acc[r]);
                }
            }
#pragma unroll
            for (int r = 0; r < 8; ++r) {
                float v = acc[r];
#pragma unroll
                for (int off = 32; off > 0; off >>= 1) v += __shfl_xor(v, off, 64);
                if (lane == 0) gates_lds[w * 8 + r] = v;
            }
            __syncthreads();

            if (tid < 8) {
                int sx = d ? (1023 - s) : s;
                const u16* pr = precomp0 + ((size_t)d * 1024 + sx) * 4096 + e0 + tid;
                float Gi = gates_lds[tid]      + bf2f(pr[0]);
                float Gf = gates_lds[8 + tid]  + bf2f(pr[1024]);
                float Gg = gates_lds[16 + tid] + bf2f(pr[2048]);
                float Go = gates_lds[24 + tid] + bf2f(pr[3072]);
                float c = sigf(Gf) * c_lds[tid] + sigf(Gi) * tanhfast(Gg);
                float h = sigf(Go) * tanhfast(c);
                c_lds[tid] = c;
                h_lds[tid] = h;
            }
            if (tid < 4) {
                u32 pk = (u32)f2bf(h_lds[2 * tid]) | ((u32)f2bf(h_lds[2 * tid + 1]) << 16);
                u64 val = ((u64)((u32)s + 1u) << 32) | pk;
                __hip_atomic_store(&hown[(size_t)s * 512 + (e0 >> 1) + tid], val,
                                   __ATOMIC_RELAXED, __HIP_MEMORY_SCOPE_AGENT);
            }
            if (tid < 8 && s == 1023) {
                cm_out[d * 1024 + e0 + tid] = c_lds[tid];
                hs_out[d * 1024 + e0 + tid] = h_lds[tid];
            }
        }
    } else {
        // ------------------------- layer 1 scan -------------------------
        for (int s = 0; s < 1024; ++s) {
            float acc[8] = {0, 0, 0, 0, 0, 0, 0, 0};
            if (s > 0) {
                const u32 want = (u32)s;
                u64* row = hown + (size_t)(s - 1) * 512 + tid * 2;
                u64 w0, w1;
                for (;;) {
                    w0 = __hip_atomic_load(&row[0], __ATOMIC_RELAXED, __HIP_MEMORY_SCOPE_AGENT);
                    w1 = __hip_atomic_load(&row[1], __ATOMIC_RELAXED, __HIP_MEMORY_SCOPE_AGENT);
                    if ((u32)(w0 >> 32) == want && (u32)(w1 >> 32) == want) break;
                    __builtin_amdgcn_s_sleep(1);
                }
                int e = tid << 2;
                int ip = e + ((e >> 3) << 1);
                hA_sh[ip]     = blo((u32)w0); hA_sh[ip + 1] = bhi((u32)w0);
                hA_sh[ip + 2] = blo((u32)w1); hA_sh[ip + 3] = bhi((u32)w1);
                __syncthreads();

                float hh[16];
                const float* g0 = &hA_sh[lane * 10];
                const float* g1 = &hA_sh[640 + lane * 10];
#pragma unroll
                for (int j2 = 0; j2 < 4; ++j2) {
                    *(v2f*)&hh[j2 * 2]     = *(const v2f*)&g0[j2 * 2];
                    *(v2f*)&hh[8 + j2 * 2] = *(const v2f*)&g1[j2 * 2];
                }
#pragma unroll
                for (int i = 0; i < 16; ++i) {
                    v4u wv4 = *(const v4u*)(wbase + i * 1024);
                    const int r = i >> 1;
                    const float* hp = &hh[(i & 1) * 8];
                    acc[r] = fmaf(blo(wv4[0]), hp[0], acc[r]);
                    acc[r] = fmaf(bhi(wv4[0]), hp[1], acc[r]);
                    acc[r] = fmaf(blo(wv4[1]), hp[2], acc[r]);
                    acc[r] = fmaf(bhi(wv4[1]), hp[3], acc[r]);
                    acc[r] = fmaf(blo(wv4[2]), hp[4], acc[r]);
                    acc[r] = fmaf(bhi(wv4[2]), hp[5], acc[r]);
                    acc[r] = fmaf(blo(wv4[3]), hp[6], acc[r]);
                    acc[r] = fmaf(bhi(wv4[3]), hp[7], acc[r]);
                }
            }
            {   // h0[s] from layer 0 (arrives ~s*T; Whh dot above overlapped the wait)
                const u32 want0 = (u32)s + 1u;
                u64* row0 = hin + (size_t)s * 512 + tid * 2;
                u64 w0, w1;
                for (;;) {
                    w0 = __hip_atomic_load(&row0[0], __ATOMIC_RELAXED, __HIP_MEMORY_SCOPE_AGENT);
                    w1 = __hip_atomic_load(&row0[1], __ATOMIC_RELAXED, __HIP_MEMORY_SCOPE_AGENT);
                    if ((u32)(w0 >> 32) == want0 && (u32)(w1 >> 32) == want0) break;
                    __builtin_amdgcn_s_sleep(1);
                }
                int e = tid << 2;
                int ip = e + ((e >> 3) << 1);
                hB_sh[ip]     = blo((u32)w0); hB_sh[ip + 1] = bhi((u32)w0);
                hB_sh[ip + 2] = blo((u32)w1); hB_sh[ip + 3] = bhi((u32)w1);
                __syncthreads();

                float hh0[16];
                const float* g0 = &hB_sh[lane * 10];
                const float* g1 = &hB_sh[640 + lane * 10];
#pragma unroll
                for (int j2 = 0; j2 < 4; ++j2) {
                    *(v2f*)&hh0[j2 * 2]     = *(const v2f*)&g0[j2 * 2];
                    *(v2f*)&hh0[8 + j2 * 2] = *(const v2f*)&g1[j2 * 2];
                }
#pragma unroll
                for (int i = 0; i < 16; ++i) {
                    v4u wv4 = wbuf[i];
                    const int r = i >> 1;
                    const float* hp = &hh0[(i & 1) * 8];
                    acc[r] = fmaf(blo(wv4[0]), hp[0], acc[r]);
                    acc[r] = fmaf(bhi(wv4[0]), hp[1], acc[r]);
                    acc[r] = fmaf(blo(wv4[1]), hp[2], acc[r]);
                    acc[r] = fmaf(bhi(wv4[1]), hp[3], acc[r]);
                    acc[r] = fmaf(blo(wv4[2]), hp[4], acc[r]);
                    acc[r] = fmaf(bhi(wv4[2]), hp[5], acc[r]);
                    acc[r] = fmaf(blo(wv4[3]), hp[6], acc[r]);
                    acc[r] = fmaf(bhi(wv4[3]), hp[7], acc[r]);
                }
            }
#pragma unroll
            for (int r = 0; r < 8; ++r) {
                float v = acc[r];
#pragma unroll
                for (int off = 32; off > 0; off >>= 1) v += __shfl_xor(v, off, 64);
                if (lane == 0) gates_lds[w * 8 + r] = v;
            }
            __syncthreads();

            if (tid < 8) {
                float Gi = gates_lds[tid]      + bias_lds[tid];
                float Gf = gates_lds[8 + tid]  + bias_lds[8 + tid];
                float Gg = gates_lds[16 + tid] + bias_lds[16 + tid];
                float Go = gates_lds[24 + tid] + bias_lds[24 + tid];
                float c = sigf(Gf) * c_lds[tid] + sigf(Gi) * tanhfast(Gg);
                float h = sigf(Go) * tanhfast(c);
                c_lds[tid] = c;
                h_lds[tid] = h;
            }
            if (tid < 4) {
                u32 pk = (u32)f2bf(h_lds[2 * tid]) | ((u32)f2bf(h_lds[2 * tid + 1]) << 16);
                u64 val = ((u64)((u32)s + 1u) << 32) | pk;
                __hip_atomic_store(&hown[(size_t)s * 512 + (e0 >> 1) + tid], val,
                                   __ATOMIC_RELAXED, __HIP_MEMORY_SCOPE_AGENT);
            }
            if (tid < 8) {
                int rrow = d ? (1023 - s) : s;
                seq_out[(size_t)rrow * 2048 + d * 1024 + e0 + tid] = h_lds[tid];
                if (s == 1023) {
                    cm_out[d * 1024 + e0 + tid] = c_lds[tid];
                    hs_out[d * 1024 + e0 + tid] = h_lds[tid];
                }
            }
        }
    }
}

// ---------------------------------------------------------------------------
extern "C" void kernel_launch(void* const* d_in, const int* in_sizes, int n_in,
                              void* d_out, int out_size, void* d_ws, size_t ws_size,
                              hipStream_t stream) {
    (void)in_sizes; (void)n_in; (void)out_size; (void)ws_size;

    const float* x       = (const float*)d_in[0];
    const float* fw0_Wih = (const float*)d_in[1];
    const float* fw0_Whh = (const float*)d_in[2];
    const float* fw0_bih = (const float*)d_in[3];
    const float* fw0_bhh = (const float*)d_in[4];
    const float* fw1_Wih = (const float*)d_in[5];
    const float* fw1_Whh = (const float*)d_in[6];
    const float* fw1_bih = (const float*)d_in[7];
    const float* fw1_bhh = (const float*)d_in[8];
    const float* bw0_Wih = (const float*)d_in[9];
    const float* bw0_Whh = (const float*)d_in[10];
    const float* bw0_bih = (const float*)d_in[11];
    const float* bw0_bhh = (const float*)d_in[12];
    const float* bw1_Wih = (const float*)d_in[13];
    const float* bw1_Whh = (const float*)d_in[14];
    const float* bw1_bih = (const float*)d_in[15];
    const float* bw1_bhh = (const float*)d_in[16];

    char* ws = (char*)d_ws;
    u16* precomp = (u16*)ws;                      // [2][1024][4096] bf16 = 16 MB
    u64* htag0   = (u64*)(ws + (16 << 20));       // [2][1024][512]       =  8 MB
    u64* htag1   = (u64*)(ws + (24 << 20));       // [2][1024][512]       =  8 MB
    float* out   = (float*)d_out;

    hipMemsetAsync(htag0, 0, (size_t)16 << 20, stream);

    dim3 g(8, 32);
    gemm_ih<<<g, 256, 0, stream>>>(x, fw0_Wih, fw0_bih, fw0_bhh, precomp, 768);
    gemm_ih<<<g, 256, 0, stream>>>(x, bw0_Wih, bw0_bih, bw0_bhh,
                                   precomp + (size_t)1024 * 4096, 768);

    lstm_fused<<<512, 256, 76096, stream>>>(
        fw0_Whh, bw0_Whh, fw1_Whh, bw1_Whh, fw1_Wih, bw1_Wih,
        fw1_bih, fw1_bhh, bw1_bih, bw1_bhh,
        precomp, htag0, htag1, out);
}

// Round 5
// 4671.341 us; speedup vs baseline: 7.9888x; 1.1892x over previous
//
#include <hip/hip_runtime.h>

typedef unsigned int u32;
typedef unsigned short u16;
typedef unsigned long long u64;
typedef __attribute__((ext_vector_type(8))) short v8s;   // 8 bf16
typedef __attribute__((ext_vector_type(4))) float v4f;
typedef __attribute__((ext_vector_type(2))) float v2f;
typedef __attribute__((ext_vector_type(4))) u32 v4u;

#define VALIDMASK 0x0001000100010001ULL

__device__ __forceinline__ float bf2f(u16 v) { return __uint_as_float(((u32)v) << 16); }
__device__ __forceinline__ u16 f2bf(float f) {
    u32 u = __float_as_uint(f);
    return (u16)((u + 0x7fffu + ((u >> 16) & 1u)) >> 16);   // RNE
}
// truncate-to-odd bf16: LSB always 1 (valid bit), |err| <= 1 ulp
__device__ __forceinline__ u32 f2bfo(float f) { return (__float_as_uint(f) >> 16) | 1u; }
__device__ __forceinline__ float blo(u32 u) { return __uint_as_float(u << 16); }
__device__ __forceinline__ float bhi(u32 u) { return __uint_as_float(u & 0xffff0000u); }
__device__ __forceinline__ float sigf(float x) { return 1.0f / (1.0f + __expf(-x)); }
__device__ __forceinline__ float tanhfast(float x) {
    float e = __expf(2.0f * x);
    return 1.0f - 2.0f / (e + 1.0f);
}
__device__ __forceinline__ v8s pack8(v4f a, v4f b) {
    v8s r;
    r[0] = (short)f2bf(a[0]); r[1] = (short)f2bf(a[1]);
    r[2] = (short)f2bf(a[2]); r[3] = (short)f2bf(a[3]);
    r[4] = (short)f2bf(b[0]); r[5] = (short)f2bf(b[1]);
    r[6] = (short)f2bf(b[2]); r[7] = (short)f2bf(b[3]);
    return r;
}

// ---------------------------------------------------------------------------
// GEMM: out[t][j] = sum_k A[t][k]*W[j][k] + bih[j] + bhh[j]. fp32 in, bf16 out.
// Layer-0 input projections only (K=768).
// ---------------------------------------------------------------------------
__global__ __launch_bounds__(256) void gemm_ih(
    const float* __restrict__ A, const float* __restrict__ W,
    const float* __restrict__ bih, const float* __restrict__ bhh,
    u16* __restrict__ out, int K)
{
    __shared__ u16 As[128][40];
    __shared__ u16 Bs[128][40];
    const int tm = blockIdx.x, tn = blockIdx.y;
    const int tid = threadIdx.x;
    const int lane = tid & 63;
    const int wv = tid >> 6;
    const int wm = wv >> 1, wn = wv & 1;
    const int fr = lane & 15, fq = lane >> 4;

    v4f acc[4][4] = {};

    for (int kt = 0; kt < K; kt += 32) {
#pragma unroll
        for (int it = 0; it < 2; ++it) {
            int q = tid + it * 256;
            int r = q >> 2;
            int c8 = (q & 3) * 8;
            const float* pa = &A[(size_t)(tm * 128 + r) * K + kt + c8];
            const float* pw = &W[(size_t)(tn * 128 + r) * K + kt + c8];
            *(v8s*)&As[r][c8] = pack8(*(const v4f*)pa, *(const v4f*)(pa + 4));
            *(v8s*)&Bs[r][c8] = pack8(*(const v4f*)pw, *(const v4f*)(pw + 4));
        }
        __syncthreads();
        v8s af[4], bfr[4];
#pragma unroll
        for (int mi = 0; mi < 4; ++mi)
            af[mi] = *(const v8s*)&As[wm * 64 + mi * 16 + fr][fq * 8];
#pragma unroll
        for (int ni = 0; ni < 4; ++ni)
            bfr[ni] = *(const v8s*)&Bs[wn * 64 + ni * 16 + fr][fq * 8];
#pragma unroll
        for (int mi = 0; mi < 4; ++mi)
#pragma unroll
            for (int ni = 0; ni < 4; ++ni)
                acc[mi][ni] = __builtin_amdgcn_mfma_f32_16x16x32_bf16(af[mi], bfr[ni], acc[mi][ni], 0, 0, 0);
        __syncthreads();
    }

#pragma unroll
    for (int ni = 0; ni < 4; ++ni) {
        int col = tn * 128 + wn * 64 + ni * 16 + fr;
        float bias = bih[col] + bhh[col];
#pragma unroll
        for (int mi = 0; mi < 4; ++mi)
#pragma unroll
            for (int j = 0; j < 4; ++j) {
                int row = tm * 128 + wm * 64 + mi * 16 + fq * 4 + j;
                out[(size_t)row * 4096 + col] = f2bf(acc[mi][ni][j] + bias);
            }
    }
}

// ---------------------------------------------------------------------------
// Fused persistent bidirectional 2-layer LSTM scan. 512 WGs (2/CU).
// role = bid>>8 (0: layer0, 1: layer1), d = (bid>>7)&1, wg = bid&127.
// WG owns 8 h-elements (32 Whh rows, bf16 in LDS). Layer-1 also holds its
// 32 Wih1 rows in registers and consumes h0 straight from layer-0's
// broadcast. Broadcast: 4 odd-LSB bf16 per u64 (valid bit = LSB of each
// half-word), relaxed agent atomics, one slot per step (memset per launch).
// ---------------------------------------------------------------------------
__global__ __launch_bounds__(256, 2) void lstm_fused(
    const float* __restrict__ fw0_Whh, const float* __restrict__ bw0_Whh,
    const float* __restrict__ fw1_Whh, const float* __restrict__ bw1_Whh,
    const float* __restrict__ fw1_Wih, const float* __restrict__ bw1_Wih,
    const float* __restrict__ fw1_bih, const float* __restrict__ fw1_bhh,
    const float* __restrict__ bw1_bih, const float* __restrict__ bw1_bhh,
    const u16*  __restrict__ precomp0,   // [2][1024][4096] bf16
    u64* htag0,                          // [2][1024][256]
    u64* htag1,                          // [2][1024][256]
    float* __restrict__ out)             // d_out base
{
    extern __shared__ char smem[];
    float* hA_sh     = (float*)(smem + 65536);  // 1280 (own-layer h, pad 2/8)
    float* hB_sh     = hA_sh + 1280;            // 1280 (h0 input, L1 only)
    float* gates_lds = hB_sh + 1280;            // 32
    float* c_lds     = gates_lds + 32;          // 8
    float* h_lds     = c_lds + 8;               // 8
    float* bias_lds  = h_lds + 8;               // 32

    const int tid = threadIdx.x;
    const int lane = tid & 63;
    const int w = tid >> 6;
    const int bid = blockIdx.x;
    const int role = bid >> 8;
    const int sub = bid & 255;
    const int d = sub >> 7;
    const int wg = sub & 127;
    const int e0 = wg << 3;

    const float* __restrict__ Whh =
        role ? (d ? bw1_Whh : fw1_Whh) : (d ? bw0_Whh : fw0_Whh);

    // Whh slice (32 rows x 1024) fp32 -> bf16 LDS, layout [gate][ei][1024].
#pragma unroll
    for (int it = 0; it < 16; ++it) {
        int q = tid + (it << 8);
        int g = q >> 10, ei = (q >> 7) & 7, cc = (q & 127) << 3;
        const float* pw = &Whh[(size_t)(g * 1024 + e0 + ei) * 1024 + cc];
        *(v8s*)(smem + (size_t)q * 16) = pack8(*(const v4f*)pw, *(const v4f*)(pw + 4));
    }

    // Layer-1: Wih1 slice -> registers (64 VGPR/lane), biases -> LDS.
    v4u wbuf[16];
    if (role) {
        const float* __restrict__ Wih = d ? bw1_Wih : fw1_Wih;
#pragma unroll
        for (int i = 0; i < 16; ++i) {
            int ei = i >> 1, c0 = ((i & 1) << 9) + (lane << 3);
            const float* p = &Wih[(size_t)(w * 1024 + e0 + ei) * 1024 + c0];
            v8s t = pack8(*(const v4f*)p, *(const v4f*)(p + 4));
            wbuf[i] = *(v4u*)&t;
        }
        if (tid < 32) {
            const float* bi = d ? bw1_bih : fw1_bih;
            const float* bh = d ? bw1_bhh : fw1_bhh;
            int g = tid >> 3, e = tid & 7;
            bias_lds[tid] = bi[g * 1024 + e0 + e] + bh[g * 1024 + e0 + e];
        }
    }
    if (tid < 8) c_lds[tid] = 0.0f;
    __syncthreads();

    const char* wbase = smem + w * 16384 + lane * 16;
    u64* hown = (role ? htag1 : htag0) + (size_t)d * 1024 * 256;
    u64* hin  = htag0 + (size_t)d * 1024 * 256;

    float* cm_out = out + role * 2048;
    float* hs_out = out + 4096 + role * 2048;
    float* seq_out = out + 8192;    // [1024][2048], role 1 writes

    const int ip = (tid << 2) + ((tid >> 1) << 1);  // padded LDS index for e=4*tid

    if (role == 0) {
        // ------------------------- layer 0 scan -------------------------
        for (int s = 0; s < 1024; ++s) {
            // Prefetch precomp row (raw u16; convert only at use, so the
            // loads fly during the poll instead of on the critical path).
            u16 ri = 0, rf = 0, rg = 0, ro = 0;
            if (tid < 8) {
                int sx = d ? (1023 - s) : s;
                const u16* pr = precomp0 + ((size_t)d * 1024 + sx) * 4096 + e0 + tid;
                ri = pr[0]; rf = pr[1024]; rg = pr[2048]; ro = pr[3072];
            }
            float acc[8] = {0, 0, 0, 0, 0, 0, 0, 0};
            if (s > 0) {
                u64* slot = hown + (size_t)(s - 1) * 256 + tid;
                u64 v;
                for (;;) {
                    v = __hip_atomic_load(slot, __ATOMIC_RELAXED, __HIP_MEMORY_SCOPE_AGENT);
                    if ((v & VALIDMASK) == VALIDMASK) break;
                    __builtin_amdgcn_s_sleep(1);
                }
                u32 lo = (u32)v, hi = (u32)(v >> 32);
                hA_sh[ip]     = blo(lo); hA_sh[ip + 1] = bhi(lo);
                hA_sh[ip + 2] = blo(hi); hA_sh[ip + 3] = bhi(hi);
                __syncthreads();

                float hh[16];
                const float* g0 = &hA_sh[lane * 10];
                const float* g1 = &hA_sh[640 + lane * 10];
#pragma unroll
                for (int j2 = 0; j2 < 4; ++j2) {
                    *(v2f*)&hh[j2 * 2]     = *(const v2f*)&g0[j2 * 2];
                    *(v2f*)&hh[8 + j2 * 2] = *(const v2f*)&g1[j2 * 2];
                }
#pragma unroll
                for (int i = 0; i < 16; ++i) {
                    v4u wv4 = *(const v4u*)(wbase + i * 1024);
                    const int r = i >> 1;
                    const float* hp = &hh[(i & 1) * 8];
                    acc[r] = fmaf(blo(wv4[0]), hp[0], acc[r]);
                    acc[r] = fmaf(bhi(wv4[0]), hp[1], acc[r]);
                    acc[r] = fmaf(blo(wv4[1]), hp[2], acc[r]);
                    acc[r] = fmaf(bhi(wv4[1]), hp[3], acc[r]);
                    acc[r] = fmaf(blo(wv4[2]), hp[4], acc[r]);
                    acc[r] = fmaf(bhi(wv4[2]), hp[5], acc[r]);
                    acc[r] = fmaf(blo(wv4[3]), hp[6], acc[r]);
                    acc[r] = fmaf(bhi(wv4[3]), hp[7], acc[r]);
                }
            }
#pragma unroll
            for (int r = 0; r < 8; ++r) {
                float v = acc[r];
#pragma unroll
                for (int off = 32; off > 0; off >>= 1) v += __shfl_xor(v, off, 64);
                if (lane == 0) gates_lds[w * 8 + r] = v;
            }
            __syncthreads();

            if (tid < 8) {
                float Gi = gates_lds[tid]      + bf2f(ri);
                float Gf = gates_lds[8 + tid]  + bf2f(rf);
                float Gg = gates_lds[16 + tid] + bf2f(rg);
                float Go = gates_lds[24 + tid] + bf2f(ro);
                float c = sigf(Gf) * c_lds[tid] + sigf(Gi) * tanhfast(Gg);
                float h = sigf(Go) * tanhfast(c);
                c_lds[tid] = c;
                h_lds[tid] = h;
            }
            if (tid < 2) {   // pack 4 odd-LSB bf16 -> one u64, publish
                int b = tid << 2;
                u32 lo = f2bfo(h_lds[b])     | (f2bfo(h_lds[b + 1]) << 16);
                u32 hi = f2bfo(h_lds[b + 2]) | (f2bfo(h_lds[b + 3]) << 16);
                u64 val = ((u64)hi << 32) | lo;
                __hip_atomic_store(&hown[(size_t)s * 256 + (e0 >> 2) + tid], val,
                                   __ATOMIC_RELAXED, __HIP_MEMORY_SCOPE_AGENT);
            }
            if (tid < 8 && s == 1023) {
                cm_out[d * 1024 + e0 + tid] = c_lds[tid];
                hs_out[d * 1024 + e0 + tid] = h_lds[tid];
            }
        }
    } else {
        // ------------------------- layer 1 scan -------------------------
        for (int s = 0; s < 1024; ++s) {
            float acc[8] = {0, 0, 0, 0, 0, 0, 0, 0};
            {   // h0[s]: usually already published (L0 runs ahead) -> cheap.
                u64* slot = hin + (size_t)s * 256 + tid;
                u64 v;
                for (;;) {
                    v = __hip_atomic_load(slot, __ATOMIC_RELAXED, __HIP_MEMORY_SCOPE_AGENT);
                    if ((v & VALIDMASK) == VALIDMASK) break;
                    __builtin_amdgcn_s_sleep(1);
                }
                u32 lo = (u32)v, hi = (u32)(v >> 32);
                hB_sh[ip]     = blo(lo); hB_sh[ip + 1] = bhi(lo);
                hB_sh[ip + 2] = blo(hi); hB_sh[ip + 3] = bhi(hi);
                __syncthreads();

                float hh0[16];
                const float* g0 = &hB_sh[lane * 10];
                const float* g1 = &hB_sh[640 + lane * 10];
#pragma unroll
                for (int j2 = 0; j2 < 4; ++j2) {
                    *(v2f*)&hh0[j2 * 2]     = *(const v2f*)&g0[j2 * 2];
                    *(v2f*)&hh0[8 + j2 * 2] = *(const v2f*)&g1[j2 * 2];
                }
                // Wih dot from registers — fills the h1[s-1] fabric window.
#pragma unroll
                for (int i = 0; i < 16; ++i) {
                    v4u wv4 = wbuf[i];
                    const int r = i >> 1;
                    const float* hp = &hh0[(i & 1) * 8];
                    acc[r] = fmaf(blo(wv4[0]), hp[0], acc[r]);
                    acc[r] = fmaf(bhi(wv4[0]), hp[1], acc[r]);
                    acc[r] = fmaf(blo(wv4[1]), hp[2], acc[r]);
                    acc[r] = fmaf(bhi(wv4[1]), hp[3], acc[r]);
                    acc[r] = fmaf(blo(wv4[2]), hp[4], acc[r]);
                    acc[r] = fmaf(bhi(wv4[2]), hp[5], acc[r]);
                    acc[r] = fmaf(blo(wv4[3]), hp[6], acc[r]);
                    acc[r] = fmaf(bhi(wv4[3]), hp[7], acc[r]);
                }
            }
            if (s > 0) {   // own recurrence h1[s-1]
                u64* slot = hown + (size_t)(s - 1) * 256 + tid;
                u64 v;
                for (;;) {
                    v = __hip_atomic_load(slot, __ATOMIC_RELAXED, __HIP_MEMORY_SCOPE_AGENT);
                    if ((v & VALIDMASK) == VALIDMASK) break;
                    __builtin_amdgcn_s_sleep(1);
                }
                u32 lo = (u32)v, hi = (u32)(v >> 32);
                hA_sh[ip]     = blo(lo); hA_sh[ip + 1] = bhi(lo);
                hA_sh[ip + 2] = blo(hi); hA_sh[ip + 3] = bhi(hi);
                __syncthreads();

                float hh[16];
                const float* g0 = &hA_sh[lane * 10];
                const float* g1 = &hA_sh[640 + lane * 10];
#pragma unroll
                for (int j2 = 0; j2 < 4; ++j2) {
                    *(v2f*)&hh[j2 * 2]     = *(const v2f*)&g0[j2 * 2];
                    *(v2f*)&hh[8 + j2 * 2] = *(const v2f*)&g1[j2 * 2];
                }
#pragma unroll
                for (int i = 0; i < 16; ++i) {
                    v4u wv4 = *(const v4u*)(wbase + i * 1024);
                    const int r = i >> 1;
                    const float* hp = &hh[(i & 1) * 8];
                    acc[r] = fmaf(blo(wv4[0]), hp[0], acc[r]);
                    acc[r] = fmaf(bhi(wv4[0]), hp[1], acc[r]);
                    acc[r] = fmaf(blo(wv4[1]), hp[2], acc[r]);
                    acc[r] = fmaf(bhi(wv4[1]), hp[3], acc[r]);
                    acc[r] = fmaf(blo(wv4[2]), hp[4], acc[r]);
                    acc[r] = fmaf(bhi(wv4[2]), hp[5], acc[r]);
                    acc[r] = fmaf(blo(wv4[3]), hp[6], acc[r]);
                    acc[r] = fmaf(bhi(wv4[3]), hp[7], acc[r]);
                }
            }
#pragma unroll
            for (int r = 0; r < 8; ++r) {
                float v = acc[r];
#pragma unroll
                for (int off = 32; off > 0; off >>= 1) v += __shfl_xor(v, off, 64);
                if (lane == 0) gates_lds[w * 8 + r] = v;
            }
            __syncthreads();

            if (tid < 8) {
                float Gi = gates_lds[tid]      + bias_lds[tid];
                float Gf = gates_lds[8 + tid]  + bias_lds[8 + tid];
                float Gg = gates_lds[16 + tid] + bias_lds[16 + tid];
                float Go = gates_lds[24 + tid] + bias_lds[24 + tid];
                float c = sigf(Gf) * c_lds[tid] + sigf(Gi) * tanhfast(Gg);
                float h = sigf(Go) * tanhfast(c);
                c_lds[tid] = c;
                h_lds[tid] = h;
            }
            if (tid < 2) {
                int b = tid << 2;
                u32 lo = f2bfo(h_lds[b])     | (f2bfo(h_lds[b + 1]) << 16);
                u32 hi = f2bfo(h_lds[b + 2]) | (f2bfo(h_lds[b + 3]) << 16);
                u64 val = ((u64)hi << 32) | lo;
                __hip_atomic_store(&hown[(size_t)s * 256 + (e0 >> 2) + tid], val,
                                   __ATOMIC_RELAXED, __HIP_MEMORY_SCOPE_AGENT);
            }
            if (tid < 8) {
                int rrow = d ? (1023 - s) : s;
                seq_out[(size_t)rrow * 2048 + d * 1024 + e0 + tid] = h_lds[tid];
                if (s == 1023) {
                    cm_out[d * 1024 + e0 + tid] = c_lds[tid];
                    hs_out[d * 1024 + e0 + tid] = h_lds[tid];
                }
            }
        }
    }
}

// ---------------------------------------------------------------------------
extern "C" void kernel_launch(void* const* d_in, const int* in_sizes, int n_in,
                              void* d_out, int out_size, void* d_ws, size_t ws_size,
                              hipStream_t stream) {
    (void)in_sizes; (void)n_in; (void)out_size; (void)ws_size;

    const float* x       = (const float*)d_in[0];
    const float* fw0_Wih = (const float*)d_in[1];
    const float* fw0_Whh = (const float*)d_in[2];
    const float* fw0_bih = (const float*)d_in[3];
    const float* fw0_bhh = (const float*)d_in[4];
    const float* fw1_Wih = (const float*)d_in[5];
    const float* fw1_Whh = (const float*)d_in[6];
    const float* fw1_bih = (const float*)d_in[7];
    const float* fw1_bhh = (const float*)d_in[8];
    const float* bw0_Wih = (const float*)d_in[9];
    const float* bw0_Whh = (const float*)d_in[10];
    const float* bw0_bih = (const float*)d_in[11];
    const float* bw0_bhh = (const float*)d_in[12];
    const float* bw1_Wih = (const float*)d_in[13];
    const float* bw1_Whh = (const float*)d_in[14];
    const float* bw1_bih = (const float*)d_in[15];
    const float* bw1_bhh = (const float*)d_in[16];

    char* ws = (char*)d_ws;
    u16* precomp = (u16*)ws;                      // [2][1024][4096] bf16 = 16 MB
    u64* htag0   = (u64*)(ws + (16 << 20));       // [2][1024][256]       =  4 MB
    u64* htag1   = (u64*)(ws + (24 << 20));       // [2][1024][256]       =  4 MB
    float* out   = (float*)d_out;

    hipMemsetAsync(htag0, 0, (size_t)16 << 20, stream);   // invalidate both

    dim3 g(8, 32);
    gemm_ih<<<g, 256, 0, stream>>>(x, fw0_Wih, fw0_bih, fw0_bhh, precomp, 768);
    gemm_ih<<<g, 256, 0, stream>>>(x, bw0_Wih, bw0_bih, bw0_bhh,
                                   precomp + (size_t)1024 * 4096, 768);

    lstm_fused<<<512, 256, 76096, stream>>>(
        fw0_Whh, bw0_Whh, fw1_Whh, bw1_Whh, fw1_Wih, bw1_Wih,
        fw1_bih, fw1_bhh, bw1_bih, bw1_bhh,
        precomp, htag0, htag1, out);
}